// Round 3
// baseline (441.809 us; speedup 1.0000x reference)
//
#include <hip/hip_runtime.h>
#include <hip/hip_bf16.h>

typedef __attribute__((ext_vector_type(8))) __bf16 bf16x8;
typedef __attribute__((ext_vector_type(4))) float floatx4;
typedef __attribute__((ext_vector_type(8))) unsigned short ushort8;

namespace {
constexpr int kC  = 256;
constexpr int kNV = 1024 * 12;        // 12288
constexpr int kP  = 8 * kNV;          // 98304 positions
constexpr float kEps = 1e-5f;

// ws layout in float units
constexpr size_t OFF_PARAMS = 0;                         // 4 stages x [a(256)|b(256)]
constexpr size_t OFF_PART   = 2048;                      // 4 stages x 8 buckets x 512
constexpr size_t OFF_WB     = 2048 + 16384;              // 163840 ushort = 81920 floats
constexpr size_t OFF_XT     = OFF_WB + 81920;            // x transposed: [P][256] bf16
constexpr size_t OFF_Y1     = OFF_XT + (size_t)kP * 256 / 2;
constexpr size_t OFF_Y2     = OFF_Y1 + (size_t)kP * 64 / 2;   // [P][256] bf16 (also y4)
constexpr size_t OFF_Y3     = OFF_Y2 + (size_t)kP * 256 / 2;
} // namespace

__device__ __forceinline__ unsigned short f2bf(float f) {
    unsigned int u = __builtin_bit_cast(unsigned int, f);
    u += 0x7FFFu + ((u >> 16) & 1u);
    return (unsigned short)(u >> 16);
}
__device__ __forceinline__ float bf2f(unsigned short h) {
    unsigned int u = ((unsigned int)h) << 16;
    return __builtin_bit_cast(float, u);
}

// convert the 4 weight matrices (We, Wa_v slice, Wo, Wf) to bf16, packed contiguously
__global__ void convw_kernel(const float* __restrict__ We, const float* __restrict__ Wa,
                             const float* __restrict__ Wo, const float* __restrict__ Wf,
                             unsigned short* __restrict__ dst)
{
    const int f = (blockIdx.x * 256 + threadIdx.x) * 4;
    const float* src; int off;
    if (f < 16384)      { src = We;            off = f; }
    else if (f < 32768) { src = Wa + 512 * 64; off = f - 16384; }
    else if (f < 98304) { src = Wo;            off = f - 32768; }
    else                { src = Wf;            off = f - 98304; }
    const float4 v = *(const float4*)&src[off];
    ushort4 o; o.x = f2bf(v.x); o.y = f2bf(v.y); o.z = f2bf(v.z); o.w = f2bf(v.w);
    *(ushort4*)&dst[f] = o;
}

// x [B,256,NV] fp32 channel-major -> xT [P][256] bf16 position-major
__global__ __launch_bounds__(256) void transpose_kernel(
    const float* __restrict__ x, unsigned short* __restrict__ xT)
{
    __shared__ float T[64][65];          // +1 pad: 2-way max on column access
    const int p0 = blockIdx.x * 64;      // never crosses b (kNV % 64 == 0)
    const int c0 = blockIdx.y * 64;
    const int b  = p0 / kNV;
    const int q0 = p0 - b * kNV;
    const int t  = threadIdx.x;

    const int cl = t >> 2;               // 0..63
    const int pq = (t & 3) * 16;         // 0,16,32,48
    const float* src = &x[(size_t)(b * kC + c0 + cl) * kNV + q0 + pq];
    #pragma unroll
    for (int i = 0; i < 4; ++i) {
        const float4 v = *(const float4*)&src[i * 4];
        T[cl][pq + i * 4 + 0] = v.x;
        T[cl][pq + i * 4 + 1] = v.y;
        T[cl][pq + i * 4 + 2] = v.z;
        T[cl][pq + i * 4 + 3] = v.w;
    }
    __syncthreads();
    const int pr = t >> 2;               // 0..63
    const int cb = (t & 3) * 16;         // 0,16,32,48
    #pragma unroll
    for (int i = 0; i < 2; ++i) {
        ushort8 o;
        #pragma unroll
        for (int j = 0; j < 8; ++j) o[j] = f2bf(T[cb + i * 8 + j][pr]);
        *(ushort8*)&xT[(size_t)(p0 + pr) * 256 + c0 + cb + i * 8] = o;
    }
}

// GEMM: Yout[p][m] = mask[p] * (sum_k W[m][k] * in[p][k] + bias[m]), bf16 MFMA.
// in[p][k]: MODE 0: xT bf16 [P][256] raw
//           MODE 1: mask*relu(a*yprev+b), yprev bf16 [P][K]
//           MODE 2: MODE1 + xT (residual) -> x1
// BN sum/sumsq fused into epilogue via bucketed atomics.
template<int BM, int MT, int K, int MODE>
__global__ __launch_bounds__(256, 2) void gemm_kernel(
    const unsigned short* __restrict__ Wb, const float* __restrict__ bias,
    const unsigned short* __restrict__ Yprev, const unsigned short* __restrict__ XT,
    const float* __restrict__ mask,
    const float* __restrict__ actA, const float* __restrict__ actB,
    unsigned short* __restrict__ Yout, float* __restrict__ partial)
{
    constexpr int LD = 40;                 // padded row stride (bf16 units)
    constexpr int FM = 4;
    constexpr int FP = (BM == 128) ? 4 : 2;
    __shared__ unsigned short As[BM * LD];
    __shared__ unsigned short Bs[128 * LD];
    __shared__ float Ms[128];

    const int tid  = threadIdx.x;
    const int lane = tid & 63, w = tid >> 6, quad = lane >> 4, lt = lane & 15;
    const int mW = (BM == 128) ? (w >> 1) * 64 : 0;
    const int pW = (BM == 128) ? (w & 1) * 64 : w * 32;
    const int pBase = blockIdx.y * 128;
    const int m0g = blockIdx.x * BM;

    if (tid < 128) Ms[tid] = mask[pBase + tid];
    __syncthreads();

    floatx4 acc[FM][FP];
    #pragma unroll
    for (int fm = 0; fm < FM; ++fm)
        #pragma unroll
        for (int fp = 0; fp < FP; ++fp) acc[fm][fp] = (floatx4)0.f;

    constexpr int AI = BM / 64;  // A-staging ushort8 loads per thread
    for (int k0 = 0; k0 < K; k0 += 32) {
        // ---- prefetch to registers ----
        ushort8 av[AI];
        #pragma unroll
        for (int i = 0; i < AI; ++i) {
            const int idx = tid + i * 256;
            const int m = idx >> 2, kq = (idx & 3) * 8;
            av[i] = *(const ushort8*)&Wb[(size_t)(m0g + m) * K + k0 + kq];
        }
        ushort8 bsv[2];
        int bp[2], bkq[2];
        #pragma unroll
        for (int i = 0; i < 2; ++i) {
            const int idx = tid + i * 256;
            const int p = idx >> 2, kq = (idx & 3) * 8;
            bp[i] = p; bkq[i] = kq;
            if constexpr (MODE == 0) {
                bsv[i] = *(const ushort8*)&XT[(size_t)(pBase + p) * 256 + k0 + kq];
            } else {
                const ushort8 y8 = *(const ushort8*)&Yprev[(size_t)(pBase + p) * K + k0 + kq];
                ushort8 x8;
                if constexpr (MODE == 2)
                    x8 = *(const ushort8*)&XT[(size_t)(pBase + p) * 256 + k0 + kq];
                const float mp = Ms[p];
                #pragma unroll
                for (int j = 0; j < 8; ++j) {
                    float v = bf2f(y8[j]);
                    v = mp * fmaxf(fmaf(actA[k0 + kq + j], v, actB[k0 + kq + j]), 0.f);
                    if constexpr (MODE == 2) v += bf2f(x8[j]);
                    bsv[i][j] = f2bf(v);
                }
            }
        }
        __syncthreads();
        #pragma unroll
        for (int i = 0; i < AI; ++i) {
            const int idx = tid + i * 256;
            *(ushort8*)&As[(idx >> 2) * LD + (idx & 3) * 8] = av[i];
        }
        #pragma unroll
        for (int i = 0; i < 2; ++i)
            *(ushort8*)&Bs[bp[i] * LD + bkq[i]] = bsv[i];
        __syncthreads();
        // ---- MFMA ----
        bf16x8 aF[FM], bF[FP];
        #pragma unroll
        for (int fm = 0; fm < FM; ++fm)
            aF[fm] = *(const bf16x8*)&As[(mW + fm * 16 + lt) * LD + quad * 8];
        #pragma unroll
        for (int fp = 0; fp < FP; ++fp)
            bF[fp] = *(const bf16x8*)&Bs[(pW + fp * 16 + lt) * LD + quad * 8];
        #pragma unroll
        for (int fm = 0; fm < FM; ++fm)
            #pragma unroll
            for (int fp = 0; fp < FP; ++fp)
                acc[fm][fp] = __builtin_amdgcn_mfma_f32_16x16x32_bf16(aF[fm], bF[fp], acc[fm][fp], 0, 0, 0);
    }

    // ---- epilogue: bias + mask, store bf16, fused stats ----
    float mpv[FP];
    #pragma unroll
    for (int fp = 0; fp < FP; ++fp) mpv[fp] = Ms[pW + fp * 16 + lt];
    float sumv[FM][4], sqv[FM][4];
    #pragma unroll
    for (int fm = 0; fm < FM; ++fm)
        #pragma unroll
        for (int i = 0; i < 4; ++i) { sumv[fm][i] = 0.f; sqv[fm][i] = 0.f; }

    #pragma unroll
    for (int fm = 0; fm < FM; ++fm) {
        float bia[4];
        #pragma unroll
        for (int i = 0; i < 4; ++i) bia[i] = bias[m0g + mW + fm * 16 + quad * 4 + i];
        #pragma unroll
        for (int fp = 0; fp < FP; ++fp) {
            const int pG = pBase + pW + fp * 16 + lt;
            float vv[4];
            #pragma unroll
            for (int i = 0; i < 4; ++i) {
                const float v = (acc[fm][fp][i] + bia[i]) * mpv[fp];
                vv[i] = v; sumv[fm][i] += v; sqv[fm][i] += v * v;
            }
            ushort4 o; o.x = f2bf(vv[0]); o.y = f2bf(vv[1]); o.z = f2bf(vv[2]); o.w = f2bf(vv[3]);
            *(ushort4*)&Yout[(size_t)pG * MT + m0g + mW + fm * 16 + quad * 4] = o;
        }
    }
    #pragma unroll
    for (int fm = 0; fm < FM; ++fm)
        #pragma unroll
        for (int i = 0; i < 4; ++i) {
            #pragma unroll
            for (int off = 1; off < 16; off <<= 1) {
                sumv[fm][i] += __shfl_xor(sumv[fm][i], off);
                sqv[fm][i]  += __shfl_xor(sqv[fm][i], off);
            }
        }
    if (lt == 0) {
        float* part = partial + (size_t)(blockIdx.y & 7) * 512;
        #pragma unroll
        for (int fm = 0; fm < FM; ++fm)
            #pragma unroll
            for (int i = 0; i < 4; ++i) {
                const int cG = m0g + mW + fm * 16 + quad * 4 + i;
                atomicAdd(&part[cG], sumv[fm][i]);
                atomicAdd(&part[256 + cG], sqv[fm][i]);
            }
    }
}

// fold BN into per-channel affine
__global__ void finalize_kernel(const float* __restrict__ part,
                                const float* __restrict__ g, const float* __restrict__ bt,
                                float* __restrict__ ab, int M)
{
    const int m = blockIdx.x * 64 + threadIdx.x;
    if (m >= M) return;
    float s = 0.f, s2 = 0.f;
    #pragma unroll
    for (int k = 0; k < 8; ++k) { s += part[k * 512 + m]; s2 += part[k * 512 + 256 + m]; }
    const float mu  = s * (1.f / kP);
    const float var = s2 * (1.f / kP) - mu * mu;
    const float A = rsqrtf(var + kEps) * g[m];
    ab[m] = A;
    ab[256 + m] = fmaf(-mu, A, bt[m]);
}

// out[c][q] = x + act3(y3) + act4(y4); all inputs [P][256] bf16 -> transpose via LDS
__global__ __launch_bounds__(256) void final_kernel(
    const unsigned short* __restrict__ xT, const unsigned short* __restrict__ y3,
    const unsigned short* __restrict__ y4,
    const float* __restrict__ p3, const float* __restrict__ p4,
    const float* __restrict__ mask, float* __restrict__ out)
{
    constexpr int TL = 264;                 // padded c-stride (ushort): 528B rows, 16B aligned
    __shared__ unsigned short TX[32 * TL];
    __shared__ unsigned short T3[32 * TL];
    __shared__ unsigned short T4[32 * TL];
    const int p0 = blockIdx.x * 32;
    const int b  = p0 / kNV;
    const int q0 = p0 - b * kNV;

    #pragma unroll
    for (int i = 0; i < 4; ++i) {
        const int idx = threadIdx.x + i * 256;
        const int p = idx >> 5, c0 = (idx & 31) * 8;
        *(ushort8*)&TX[p * TL + c0] = *(const ushort8*)&xT[(size_t)(p0 + p) * 256 + c0];
        *(ushort8*)&T3[p * TL + c0] = *(const ushort8*)&y3[(size_t)(p0 + p) * 256 + c0];
        *(ushort8*)&T4[p * TL + c0] = *(const ushort8*)&y4[(size_t)(p0 + p) * 256 + c0];
    }
    __syncthreads();

    const int qv = (threadIdx.x & 15) * 2;
    const int cb = threadIdx.x >> 4;
    const float m0v = mask[p0 + qv], m1v = mask[p0 + qv + 1];
    #pragma unroll
    for (int j = 0; j < 16; ++j) {
        const int c = cb + j * 16;
        const float a3 = p3[c], b3 = p3[256 + c], a4 = p4[c], b4 = p4[256 + c];
        const size_t ro = (size_t)(b * kC + c) * kNV + q0 + qv;
        const float x0v = bf2f(TX[qv * TL + c]),       x1v = bf2f(TX[(qv + 1) * TL + c]);
        const float v30 = bf2f(T3[qv * TL + c]),       v31 = bf2f(T3[(qv + 1) * TL + c]);
        const float v40 = bf2f(T4[qv * TL + c]),       v41 = bf2f(T4[(qv + 1) * TL + c]);
        float2 o;
        o.x = x0v + m0v * (fmaxf(fmaf(a3, v30, b3), 0.f) + fmaxf(fmaf(a4, v40, b4), 0.f));
        o.y = x1v + m1v * (fmaxf(fmaf(a3, v31, b3), 0.f) + fmaxf(fmaf(a4, v41, b4), 0.f));
        *(float2*)&out[ro] = o;
    }
}

extern "C" void kernel_launch(void* const* d_in, const int* in_sizes, int n_in,
                              void* d_out, int out_size, void* d_ws, size_t ws_size,
                              hipStream_t stream)
{
    const float* x    = (const float*)d_in[0];
    const float* mask = (const float*)d_in[1];
    const float* We   = (const float*)d_in[2];
    const float* be   = (const float*)d_in[3];
    const float* ge   = (const float*)d_in[4];
    const float* bne  = (const float*)d_in[5];
    const float* Wa   = (const float*)d_in[6];
    const float* ba   = (const float*)d_in[7];
    const float* ga   = (const float*)d_in[8];
    const float* bna  = (const float*)d_in[9];
    const float* Wo   = (const float*)d_in[10];
    const float* bo   = (const float*)d_in[11];
    const float* go   = (const float*)d_in[12];
    const float* bno  = (const float*)d_in[13];
    const float* Wf   = (const float*)d_in[14];
    const float* bf   = (const float*)d_in[15];
    const float* gf   = (const float*)d_in[16];
    const float* bnf  = (const float*)d_in[17];
    float* out = (float*)d_out;
    float* ws  = (float*)d_ws;

    float* params = ws + OFF_PARAMS;
    float* part   = ws + OFF_PART;
    unsigned short* Wb = (unsigned short*)(ws + OFF_WB);
    unsigned short* xT = (unsigned short*)(ws + OFF_XT);
    unsigned short* y1 = (unsigned short*)(ws + OFF_Y1);
    unsigned short* y2 = (unsigned short*)(ws + OFF_Y2);   // later reused as y4
    unsigned short* y3 = (unsigned short*)(ws + OFF_Y3);

    hipMemsetAsync(part, 0, 16384 * sizeof(float), stream);
    convw_kernel<<<160, 256, 0, stream>>>(We, Wa, Wo, Wf, Wb);
    transpose_kernel<<<dim3(kP / 64, 4), 256, 0, stream>>>(x, xT);

    const dim3 blk(256);
    const int PT = kP / 128;   // 768

    // stage 1: y1 = mask*(We @ x + be)  [P][64]
    gemm_kernel<64, 64, 256, 0><<<dim3(1, PT), blk, 0, stream>>>(
        Wb, be, nullptr, xT, mask, nullptr, nullptr, y1, part);
    finalize_kernel<<<1, 64, 0, stream>>>(part, ge, bne, params, 64);

    // stage 2: y2 = mask*(Wa_v @ act1(y1) + ba_v)  [P][256]
    gemm_kernel<128, 256, 64, 1><<<dim3(2, PT), blk, 0, stream>>>(
        Wb + 16384, ba + 512, y1, nullptr, mask, params, params + 256, y2, part + 4096);
    finalize_kernel<<<4, 64, 0, stream>>>(part + 4096, ga + 512, bna + 512, params + 512, 256);

    // stage 3: y3 = mask*(Wo @ act2(y2) + bo)
    gemm_kernel<128, 256, 256, 1><<<dim3(2, PT), blk, 0, stream>>>(
        Wb + 32768, bo, y2, nullptr, mask, params + 512, params + 768, y3, part + 8192);
    finalize_kernel<<<4, 64, 0, stream>>>(part + 8192, go, bno, params + 1024, 256);

    // stage 4: y4 = mask*(Wf @ (x + act3(y3)) + bf)  (into y2's buffer)
    gemm_kernel<128, 256, 256, 2><<<dim3(2, PT), blk, 0, stream>>>(
        Wb + 98304, bf, y3, xT, mask, params + 1024, params + 1280, y2, part + 12288);
    finalize_kernel<<<4, 64, 0, stream>>>(part + 12288, gf, bnf, params + 1536, 256);

    // final: out = x + act3(y3) + act4(y4)
    final_kernel<<<kP / 32, blk, 0, stream>>>(
        xT, y3, y2, params + 1024, params + 1536, mask, out);
}